// Round 10
// baseline (140.540 us; speedup 1.0000x reference)
//
#include <hip/hip_runtime.h>
#include <hip/hip_bf16.h>

// AttentionNTKChoiceModel — r10: r9 verbatim + 3 idempotent attn re-launches
// (measurement round: attn_us = (dur_r10 - dur_r9)/3; attn rewrites identical
// bytes to vws, so correctness and graph capture are unaffected).
// B=32, L=512, D=128, H=8, D0=D2=32.

typedef __attribute__((ext_vector_type(8))) short bf16x8;
typedef __attribute__((ext_vector_type(4))) float f32x4;
typedef __attribute__((ext_vector_type(8))) unsigned short ushort8;
typedef __attribute__((ext_vector_type(4))) unsigned short ushort4v;

#define NEG (-10000.0f)
#define LOG2E 1.4426950408889634f
#define QSCALE (0.17677669529663687f * LOG2E)

__device__ __forceinline__ unsigned short bf16_rn(float x, float* rep) {
  unsigned u = __float_as_uint(x);
  unsigned r = (u + 0x7FFFu + ((u >> 16) & 1u)) >> 16;
  *rep = __uint_as_float(r << 16);
  return (unsigned short)r;
}

// grid 1057 x 256: [0,1024) X-split, [1024,1056) W1/W2-split, 1056 u+pad
__global__ __launch_bounds__(256) void convert_kernel(
    const float* __restrict__ X, const float* __restrict__ W1,
    const float* __restrict__ W2, const float* __restrict__ W3,
    const float* __restrict__ w,
    unsigned short* __restrict__ X2, unsigned short* __restrict__ Wc) {
  const int bx = blockIdx.x, t = threadIdx.x;
  if (bx < 1056) {
    const float* src;
    unsigned short* dst;
    int row, c;
    if (bx < 1024) {
      const size_t flat = (size_t)bx * 2048 + t * 8;
      row = (int)(flat >> 7); c = (int)(flat & 127);
      src = &X[flat];
      dst = &X2[(size_t)row * 256 + c];
    } else {
      const int flat = (bx - 1024) * 2048 + t * 8;
      row = flat >> 7; c = flat & 127;
      src = (row < 256) ? &W1[(size_t)row * 128 + c]
                        : &W2[(size_t)(row - 256) * 128 + c];
      dst = &Wc[(size_t)row * 256 + c];
    }
    float xv[8];
    *(float4*)&xv[0] = *(const float4*)src;
    *(float4*)&xv[4] = *(const float4*)(src + 4);
    ushort8 hi, lo;
#pragma unroll
    for (int i = 0; i < 8; ++i) {
      float hf, lf;
      hi[i] = bf16_rn(xv[i], &hf);
      lo[i] = bf16_rn(xv[i] - hf, &lf);
    }
    *(ushort8*)dst = hi;
    *(ushort8*)(dst + 128) = lo;
  } else {
    __shared__ float uS[8][128];
    if (t < 128) {
#pragma unroll
      for (int h = 0; h < 8; ++h) {
        float acc = 0.f;
#pragma unroll
        for (int d = 0; d < 32; ++d)
          acc += W3[(h * 32 + d) * 128 + t] * w[h * 32 + d];
        uS[h][t] = acc * 0.3535533905932738f;  // 1/sqrt(8)
      }
    }
    __syncthreads();
    {
      const int r = t >> 5, c = (t & 31) * 4;
      float4 v = *(float4*)&uS[r][c];
      float vv[4] = {v.x, v.y, v.z, v.w};
      ushort4v hi, lo;
#pragma unroll
      for (int i = 0; i < 4; ++i) {
        float hf, lf;
        hi[i] = bf16_rn(vv[i], &hf);
        lo[i] = bf16_rn(vv[i] - hf, &lf);
      }
      *(ushort4v*)&Wc[(size_t)(512 + r) * 256 + c] = hi;
      *(ushort4v*)&Wc[(size_t)(512 + r) * 256 + 128 + c] = lo;
    }
    const ushort8 z = {};
    for (int i = t; i < 1792; i += 256)  // zero rows 520..575
      *(ushort8*)&Wc[(size_t)520 * 256 + i * 8] = z;
  }
}

// [16384,576] GEMM, exact 4-term: diag (hh+ll) + shifted (hl+lh).
// Block 256thr (4 waves), tile 64x64, K chunks of 64 over the 256-wide [hi|lo].
__global__ __launch_bounds__(256) void proj_kernel(
    const unsigned short* __restrict__ X2, const unsigned short* __restrict__ Wc,
    unsigned short* __restrict__ Q2, unsigned short* __restrict__ K2,
    float* __restrict__ Vw) {
  __shared__ unsigned short XS[64][72], WSd[64][72], WSx[64][72];
  const int t = threadIdx.x;
  const int row0 = blockIdx.x * 64, col0 = blockIdx.y * 64;
  const int w = t >> 6, lane = t & 63, g = lane >> 4, r16 = lane & 15;
  const int srow = t >> 2, su = (t & 3) * 16;

  f32x4 acc[4];
#pragma unroll
  for (int n = 0; n < 4; ++n) acc[n] = (f32x4){0.f, 0.f, 0.f, 0.f};

  for (int kc = 0; kc < 256; kc += 64) {
    const int kcx = (kc + 128) & 255;
    if (kc) __syncthreads();
    {
      const size_t xo = (size_t)(row0 + srow) * 256 + kc + su;
      const size_t wd = (size_t)(col0 + srow) * 256 + kc + su;
      const size_t wx = (size_t)(col0 + srow) * 256 + kcx + su;
      ushort8 a = *(const ushort8*)&X2[xo];
      ushort8 b = *(const ushort8*)&X2[xo + 8];
      ushort8 c = *(const ushort8*)&Wc[wd];
      ushort8 d = *(const ushort8*)&Wc[wd + 8];
      ushort8 e = *(const ushort8*)&Wc[wx];
      ushort8 f = *(const ushort8*)&Wc[wx + 8];
      *(ushort8*)&XS[srow][su] = a;
      *(ushort8*)&XS[srow][su + 8] = b;
      *(ushort8*)&WSd[srow][su] = c;
      *(ushort8*)&WSd[srow][su + 8] = d;
      *(ushort8*)&WSx[srow][su] = e;
      *(ushort8*)&WSx[srow][su + 8] = f;
    }
    __syncthreads();
#pragma unroll
    for (int ks = 0; ks < 2; ++ks) {
      bf16x8 ah = *(const bf16x8*)&XS[w * 16 + r16][ks * 32 + g * 8];
#pragma unroll
      for (int n = 0; n < 4; ++n) {
        bf16x8 bd = *(const bf16x8*)&WSd[n * 16 + r16][ks * 32 + g * 8];
        bf16x8 bx = *(const bf16x8*)&WSx[n * 16 + r16][ks * 32 + g * 8];
        acc[n] = __builtin_amdgcn_mfma_f32_16x16x32_bf16(ah, bd, acc[n], 0, 0, 0);
        acc[n] = __builtin_amdgcn_mfma_f32_16x16x32_bf16(ah, bx, acc[n], 0, 0, 0);
      }
    }
  }
  // C layout: row = w*16 + g*4 + r, col = col0 + n*16 + r16 (verified r2)
#pragma unroll
  for (int n = 0; n < 4; ++n) {
    const int col = col0 + n * 16 + r16;
#pragma unroll
    for (int r = 0; r < 4; ++r) {
      const int row = row0 + w * 16 + g * 4 + r;
      const int b = row >> 9, l = row & 511;
      const float val = acc[n][r];
      if (col < 256) {
        const float sv = val * QSCALE;
        float hf, lf;
        const unsigned short hb = bf16_rn(sv, &hf);
        const unsigned short lb = bf16_rn(sv - hf, &lf);
        const size_t o = ((size_t)(b * 8 + (col >> 5)) * 512 + l) * 64 + (col & 31);
        Q2[o] = hb; Q2[o + 32] = lb;
      } else if (col < 512) {
        const int c2 = col - 256;
        float hf, lf;
        const unsigned short hb = bf16_rn(val, &hf);
        const unsigned short lb = bf16_rn(val - hf, &lf);
        const size_t o = ((size_t)(b * 8 + (c2 >> 5)) * 512 + l) * 64 + (c2 & 31);
        K2[o] = hb; K2[o + 32] = lb;
      } else if (col < 520) {
        Vw[(size_t)(b * 8 + (col - 512)) * 512 + l] = val;
      }
    }
  }
}

// Block (qhalf, h, b), 512 thr, whole head in LDS (1 barrier).
// Lane-local online softmax: no cross-lane ops until the final merge.
__global__ __launch_bounds__(512, 4) void attn_kernel(
    const unsigned short* __restrict__ Q2, const unsigned short* __restrict__ K2,
    const float* __restrict__ Vw, const int* __restrict__ mask,
    float* __restrict__ vws) {
  __shared__ unsigned short KS[512][72];  // 72 KB
  __shared__ float VwS[512], biasS[512];
  const int t = threadIdx.x;
  const int w = t >> 6, lane = t & 63, g = lane >> 4, r16 = lane & 15;
  const int qbase = blockIdx.x * 256, h = blockIdx.y, b = blockIdx.z;
  const size_t headoff = (size_t)(b * 8 + h) * 512;

#pragma unroll
  for (int i = 0; i < 8; ++i) {
    const int flat = i * 512 + t, row = flat >> 3, cg = (flat & 7) * 8;
    *(ushort8*)&KS[row][cg] = *(const ushort8*)&K2[(headoff + row) * 64 + cg];
  }
  VwS[t] = Vw[headoff + t];
  biasS[t] = mask[b * 512 + t] ? 0.f : NEG * LOG2E;

  bf16x8 qf[2][2];  // [qtile][hi/lo]
#pragma unroll
  for (int qt = 0; qt < 2; ++qt)
#pragma unroll
    for (int ks = 0; ks < 2; ++ks)
      qf[qt][ks] = *(const bf16x8*)
          &Q2[(headoff + qbase + w * 32 + qt * 16 + r16) * 64 + ks * 32 + g * 8];

  __syncthreads();

  float m[2] = {-3e38f, -3e38f}, ls[2] = {0.f, 0.f}, vv[2] = {0.f, 0.f};

  for (int c = 0; c < 8; ++c) {
    bf16x8 a0[4], a1[4];
#pragma unroll
    for (int j = 0; j < 4; ++j) {
      a0[j] = *(const bf16x8*)&KS[c * 64 + j * 16 + r16][g * 8];
      a1[j] = *(const bf16x8*)&KS[c * 64 + j * 16 + r16][32 + g * 8];
    }
    float4 bs4[4], vw4[4];
#pragma unroll
    for (int j = 0; j < 4; ++j) {
      bs4[j] = *(const float4*)&biasS[c * 64 + j * 16 + g * 4];
      vw4[j] = *(const float4*)&VwS[c * 64 + j * 16 + g * 4];
    }
#pragma unroll
    for (int qt = 0; qt < 2; ++qt) {
      f32x4 sc[4];
#pragma unroll
      for (int j = 0; j < 4; ++j) {
        f32x4 z = (f32x4){bs4[j].x, bs4[j].y, bs4[j].z, bs4[j].w};  // bias in C
        z = __builtin_amdgcn_mfma_f32_16x16x32_bf16(a0[j], qf[qt][0], z, 0, 0, 0);
        z = __builtin_amdgcn_mfma_f32_16x16x32_bf16(a0[j], qf[qt][1], z, 0, 0, 0);
        z = __builtin_amdgcn_mfma_f32_16x16x32_bf16(a1[j], qf[qt][0], z, 0, 0, 0);
        sc[j] = z;
      }
      float cm01 = fmaxf(fmaxf(sc[0][0], sc[0][1]), fmaxf(sc[0][2], sc[0][3]));
      float cm23 = fmaxf(fmaxf(sc[1][0], sc[1][1]), fmaxf(sc[1][2], sc[1][3]));
      float cm45 = fmaxf(fmaxf(sc[2][0], sc[2][1]), fmaxf(sc[2][2], sc[2][3]));
      float cm67 = fmaxf(fmaxf(sc[3][0], sc[3][1]), fmaxf(sc[3][2], sc[3][3]));
      const float cmax = fmaxf(fmaxf(cm01, cm23), fmaxf(cm45, cm67));
      const float mnew = fmaxf(m[qt], cmax);
      const float f = __builtin_amdgcn_exp2f(m[qt] - mnew);
      m[qt] = mnew;
      float l = ls[qt] * f, v = vv[qt] * f;
#pragma unroll
      for (int j = 0; j < 4; ++j) {
        const float p0 = __builtin_amdgcn_exp2f(sc[j][0] - mnew);
        const float p1 = __builtin_amdgcn_exp2f(sc[j][1] - mnew);
        const float p2 = __builtin_amdgcn_exp2f(sc[j][2] - mnew);
        const float p3 = __builtin_amdgcn_exp2f(sc[j][3] - mnew);
        l += (p0 + p1) + (p2 + p3);
        v = fmaf(p0, vw4[j].x, v);
        v = fmaf(p1, vw4[j].y, v);
        v = fmaf(p2, vw4[j].z, v);
        v = fmaf(p3, vw4[j].w, v);
      }
      ls[qt] = l; vv[qt] = v;
    }
  }
  // split-softmax merge across the 4 lane groups (xor 16, then 32)
#pragma unroll
  for (int qt = 0; qt < 2; ++qt) {
#pragma unroll
    for (int off = 16; off <= 32; off <<= 1) {
      const float mo = __shfl_xor(m[qt], off);
      const float lo_ = __shfl_xor(ls[qt], off);
      const float vo = __shfl_xor(vv[qt], off);
      const float m2 = fmaxf(m[qt], mo);
      const float fa = __builtin_amdgcn_exp2f(m[qt] - m2);
      const float fb = __builtin_amdgcn_exp2f(mo - m2);
      ls[qt] = ls[qt] * fa + lo_ * fb;
      vv[qt] = vv[qt] * fa + vo * fb;
      m[qt] = m2;
    }
  }
  if (lane < 16) {
#pragma unroll
    for (int qt = 0; qt < 2; ++qt)
      vws[headoff + qbase + w * 32 + qt * 16 + lane] = vv[qt] / ls[qt];
  }
}

__global__ __launch_bounds__(512) void final_kernel(
    const float* __restrict__ vws, const int* __restrict__ mask,
    float* __restrict__ out) {
  const int b = blockIdx.x, l = threadIdx.x;  // grid 32, block 512
  __shared__ float redm[8], reds[8];
  float v = 0.f;
#pragma unroll
  for (int h = 0; h < 8; ++h) v += vws[(size_t)(b * 8 + h) * 512 + l];
  if (mask[b * 512 + l] == 0) v = NEG;
  float mx = v;
#pragma unroll
  for (int off = 32; off >= 1; off >>= 1) mx = fmaxf(mx, __shfl_xor(mx, off));
  if ((l & 63) == 0) redm[l >> 6] = mx;
  __syncthreads();
  float M = redm[0];
#pragma unroll
  for (int i = 1; i < 8; ++i) M = fmaxf(M, redm[i]);
  const float e = __expf(v - M);
  float sm = e;
#pragma unroll
  for (int off = 32; off >= 1; off >>= 1) sm += __shfl_xor(sm, off);
  if ((l & 63) == 0) reds[l >> 6] = sm;
  __syncthreads();
  float S = 0.f;
#pragma unroll
  for (int i = 0; i < 8; ++i) S += reds[i];
  out[b * 512 + l] = e / S;
}

extern "C" void kernel_launch(void* const* d_in, const int* in_sizes, int n_in,
                              void* d_out, int out_size, void* d_ws, size_t ws_size,
                              hipStream_t stream) {
  const float* X  = (const float*)d_in[0];
  const int*  mk  = (const int*)d_in[1];
  const float* W1 = (const float*)d_in[2];
  const float* W2 = (const float*)d_in[3];
  const float* W3 = (const float*)d_in[4];
  const float* w  = (const float*)d_in[5];
  float* out = (float*)d_out;

  char* ws = (char*)d_ws;
  unsigned short* X2 = (unsigned short*)ws;                 // 16384*256  = 8 MB
  unsigned short* Wc = X2 + (size_t)16384 * 256;            //   576*256  = 288 KB
  unsigned short* Q2 = Wc + (size_t)576 * 256;              // 32*8*512*64 = 16 MB
  unsigned short* K2 = Q2 + (size_t)32 * 8 * 512 * 64;      // 16 MB
  float* Vw  = (float*)(K2 + (size_t)32 * 8 * 512 * 64);    // 512 KB
  float* vws = Vw + (size_t)32 * 8 * 512;                   // 512 KB

  convert_kernel<<<dim3(1057), dim3(256), 0, stream>>>(X, W1, W2, W3, w, X2, Wc);
  proj_kernel<<<dim3(256, 9), dim3(256), 0, stream>>>(X2, Wc, Q2, K2, Vw);
  // real attn + 3 idempotent re-launches (measurement: identical bytes to vws)
  attn_kernel<<<dim3(2, 8, 32), dim3(512), 0, stream>>>(Q2, K2, Vw, mk, vws);
  attn_kernel<<<dim3(2, 8, 32), dim3(512), 0, stream>>>(Q2, K2, Vw, mk, vws);
  attn_kernel<<<dim3(2, 8, 32), dim3(512), 0, stream>>>(Q2, K2, Vw, mk, vws);
  attn_kernel<<<dim3(2, 8, 32), dim3(512), 0, stream>>>(Q2, K2, Vw, mk, vws);
  final_kernel<<<dim3(32), dim3(512), 0, stream>>>(vws, mk, out);
}

// Round 11
// 86.403 us; speedup vs baseline: 1.6266x; 1.6266x over previous
//
#include <hip/hip_runtime.h>
#include <hip/hip_bf16.h>

// AttentionNTKChoiceModel — r11: r9 base; attn merged to one block per (b,h)
// (1024 thr), split-half staging with issue-early/write-late overlap.
// Measured budget (r10): attn 25.8us, proj+convert ~25us, final+gaps ~10us.
// B=32, L=512, D=128, H=8, D0=D2=32.

typedef __attribute__((ext_vector_type(8))) short bf16x8;
typedef __attribute__((ext_vector_type(4))) float f32x4;
typedef __attribute__((ext_vector_type(8))) unsigned short ushort8;
typedef __attribute__((ext_vector_type(4))) unsigned short ushort4v;

#define NEG (-10000.0f)
#define LOG2E 1.4426950408889634f
#define QSCALE (0.17677669529663687f * LOG2E)

__device__ __forceinline__ unsigned short bf16_rn(float x, float* rep) {
  unsigned u = __float_as_uint(x);
  unsigned r = (u + 0x7FFFu + ((u >> 16) & 1u)) >> 16;
  *rep = __uint_as_float(r << 16);
  return (unsigned short)r;
}

// grid 1057 x 256: [0,1024) X-split, [1024,1056) W1/W2-split, 1056 u+pad
__global__ __launch_bounds__(256) void convert_kernel(
    const float* __restrict__ X, const float* __restrict__ W1,
    const float* __restrict__ W2, const float* __restrict__ W3,
    const float* __restrict__ w,
    unsigned short* __restrict__ X2, unsigned short* __restrict__ Wc) {
  const int bx = blockIdx.x, t = threadIdx.x;
  if (bx < 1056) {
    const float* src;
    unsigned short* dst;
    int row, c;
    if (bx < 1024) {
      const size_t flat = (size_t)bx * 2048 + t * 8;
      row = (int)(flat >> 7); c = (int)(flat & 127);
      src = &X[flat];
      dst = &X2[(size_t)row * 256 + c];
    } else {
      const int flat = (bx - 1024) * 2048 + t * 8;
      row = flat >> 7; c = flat & 127;
      src = (row < 256) ? &W1[(size_t)row * 128 + c]
                        : &W2[(size_t)(row - 256) * 128 + c];
      dst = &Wc[(size_t)row * 256 + c];
    }
    float xv[8];
    *(float4*)&xv[0] = *(const float4*)src;
    *(float4*)&xv[4] = *(const float4*)(src + 4);
    ushort8 hi, lo;
#pragma unroll
    for (int i = 0; i < 8; ++i) {
      float hf, lf;
      hi[i] = bf16_rn(xv[i], &hf);
      lo[i] = bf16_rn(xv[i] - hf, &lf);
    }
    *(ushort8*)dst = hi;
    *(ushort8*)(dst + 128) = lo;
  } else {
    __shared__ float uS[8][128];
    if (t < 128) {
#pragma unroll
      for (int h = 0; h < 8; ++h) {
        float acc = 0.f;
#pragma unroll
        for (int d = 0; d < 32; ++d)
          acc += W3[(h * 32 + d) * 128 + t] * w[h * 32 + d];
        uS[h][t] = acc * 0.3535533905932738f;  // 1/sqrt(8)
      }
    }
    __syncthreads();
    {
      const int r = t >> 5, c = (t & 31) * 4;
      float4 v = *(float4*)&uS[r][c];
      float vv[4] = {v.x, v.y, v.z, v.w};
      ushort4v hi, lo;
#pragma unroll
      for (int i = 0; i < 4; ++i) {
        float hf, lf;
        hi[i] = bf16_rn(vv[i], &hf);
        lo[i] = bf16_rn(vv[i] - hf, &lf);
      }
      *(ushort4v*)&Wc[(size_t)(512 + r) * 256 + c] = hi;
      *(ushort4v*)&Wc[(size_t)(512 + r) * 256 + 128 + c] = lo;
    }
    const ushort8 z = {};
    for (int i = t; i < 1792; i += 256)  // zero rows 520..575
      *(ushort8*)&Wc[(size_t)520 * 256 + i * 8] = z;
  }
}

// [16384,576] GEMM, exact 4-term: diag (hh+ll) + shifted (hl+lh).
// Block 256thr (4 waves), tile 64x64, K chunks of 64 over the 256-wide [hi|lo].
__global__ __launch_bounds__(256) void proj_kernel(
    const unsigned short* __restrict__ X2, const unsigned short* __restrict__ Wc,
    unsigned short* __restrict__ Q2, unsigned short* __restrict__ K2,
    float* __restrict__ Vw) {
  __shared__ unsigned short XS[64][72], WSd[64][72], WSx[64][72];
  const int t = threadIdx.x;
  const int row0 = blockIdx.x * 64, col0 = blockIdx.y * 64;
  const int w = t >> 6, lane = t & 63, g = lane >> 4, r16 = lane & 15;
  const int srow = t >> 2, su = (t & 3) * 16;

  f32x4 acc[4];
#pragma unroll
  for (int n = 0; n < 4; ++n) acc[n] = (f32x4){0.f, 0.f, 0.f, 0.f};

  for (int kc = 0; kc < 256; kc += 64) {
    const int kcx = (kc + 128) & 255;
    if (kc) __syncthreads();
    {
      const size_t xo = (size_t)(row0 + srow) * 256 + kc + su;
      const size_t wd = (size_t)(col0 + srow) * 256 + kc + su;
      const size_t wx = (size_t)(col0 + srow) * 256 + kcx + su;
      ushort8 a = *(const ushort8*)&X2[xo];
      ushort8 b = *(const ushort8*)&X2[xo + 8];
      ushort8 c = *(const ushort8*)&Wc[wd];
      ushort8 d = *(const ushort8*)&Wc[wd + 8];
      ushort8 e = *(const ushort8*)&Wc[wx];
      ushort8 f = *(const ushort8*)&Wc[wx + 8];
      *(ushort8*)&XS[srow][su] = a;
      *(ushort8*)&XS[srow][su + 8] = b;
      *(ushort8*)&WSd[srow][su] = c;
      *(ushort8*)&WSd[srow][su + 8] = d;
      *(ushort8*)&WSx[srow][su] = e;
      *(ushort8*)&WSx[srow][su + 8] = f;
    }
    __syncthreads();
#pragma unroll
    for (int ks = 0; ks < 2; ++ks) {
      bf16x8 ah = *(const bf16x8*)&XS[w * 16 + r16][ks * 32 + g * 8];
#pragma unroll
      for (int n = 0; n < 4; ++n) {
        bf16x8 bd = *(const bf16x8*)&WSd[n * 16 + r16][ks * 32 + g * 8];
        bf16x8 bx = *(const bf16x8*)&WSx[n * 16 + r16][ks * 32 + g * 8];
        acc[n] = __builtin_amdgcn_mfma_f32_16x16x32_bf16(ah, bd, acc[n], 0, 0, 0);
        acc[n] = __builtin_amdgcn_mfma_f32_16x16x32_bf16(ah, bx, acc[n], 0, 0, 0);
      }
    }
  }
  // C layout: row = w*16 + g*4 + r, col = col0 + n*16 + r16 (verified r2)
#pragma unroll
  for (int n = 0; n < 4; ++n) {
    const int col = col0 + n * 16 + r16;
#pragma unroll
    for (int r = 0; r < 4; ++r) {
      const int row = row0 + w * 16 + g * 4 + r;
      const int b = row >> 9, l = row & 511;
      const float val = acc[n][r];
      if (col < 256) {
        const float sv = val * QSCALE;
        float hf, lf;
        const unsigned short hb = bf16_rn(sv, &hf);
        const unsigned short lb = bf16_rn(sv - hf, &lf);
        const size_t o = ((size_t)(b * 8 + (col >> 5)) * 512 + l) * 64 + (col & 31);
        Q2[o] = hb; Q2[o + 32] = lb;
      } else if (col < 512) {
        const int c2 = col - 256;
        float hf, lf;
        const unsigned short hb = bf16_rn(val, &hf);
        const unsigned short lb = bf16_rn(val - hf, &lf);
        const size_t o = ((size_t)(b * 8 + (c2 >> 5)) * 512 + l) * 64 + (c2 & 31);
        K2[o] = hb; K2[o + 32] = lb;
      } else if (col < 520) {
        Vw[(size_t)(b * 8 + (col - 512)) * 512 + l] = val;
      }
    }
  }
}

// One block per (b,h): 1024 thr (16 waves), whole 512-key head in LDS.
// Split-half staging: write A, issue B loads, compute 0-3, write B, compute 4-7.
__global__ __launch_bounds__(1024, 4) void attn_kernel(
    const unsigned short* __restrict__ Q2, const unsigned short* __restrict__ K2,
    const float* __restrict__ Vw, const int* __restrict__ mask,
    float* __restrict__ vws) {
  __shared__ unsigned short KS[512][72];  // 73,728 B
  __shared__ float VwS[512], biasS[512];  // 4 KB
  const int t = threadIdx.x;
  const int w = t >> 6, lane = t & 63, g = lane >> 4, r16 = lane & 15;
  const int head = blockIdx.x;            // b*8 + h
  const int b = head >> 3;
  const size_t headoff = (size_t)head * 512;

  // ---- phase A loads (keys 0..255) ----
  ushort8 kA0, kA1;
  {
    const int f0 = t, f1 = 1024 + t;  // ushort8 indices 0..2047
    kA0 = *(const ushort8*)&K2[headoff * 64 + f0 * 8];
    kA1 = *(const ushort8*)&K2[headoff * 64 + f1 * 8];
  }
  float vwA = 0.f, biasA = 0.f;
  if (t < 256) vwA = Vw[headoff + t];
  else if (t < 512) biasA = mask[b * 512 + (t - 256)] ? 0.f : NEG * LOG2E;

  // write A
  {
    const int f0 = t, f1 = 1024 + t;
    *(ushort8*)&KS[f0 >> 3][(f0 & 7) * 8] = kA0;
    *(ushort8*)&KS[f1 >> 3][(f1 & 7) * 8] = kA1;
  }
  if (t < 256) VwS[t] = vwA;
  else if (t < 512) biasS[t - 256] = biasA;

  // ---- issue phase B loads now (hide HBM latency under compute A) ----
  ushort8 kB0, kB1;
  {
    const int f2 = 2048 + t, f3 = 3072 + t;
    kB0 = *(const ushort8*)&K2[headoff * 64 + f2 * 8];
    kB1 = *(const ushort8*)&K2[headoff * 64 + f3 * 8];
  }
  float vwB = 0.f, biasB = 0.f;
  if (t < 256) vwB = Vw[headoff + 256 + t];
  else if (t < 512) biasB = mask[b * 512 + 256 + (t - 256)] ? 0.f : NEG * LOG2E;

  // Q fragments (wave w owns q rows w*32..w*32+31)
  bf16x8 qf[2][2];  // [qtile][hi/lo]
#pragma unroll
  for (int qt = 0; qt < 2; ++qt)
#pragma unroll
    for (int ks = 0; ks < 2; ++ks)
      qf[qt][ks] = *(const bf16x8*)
          &Q2[(headoff + w * 32 + qt * 16 + r16) * 64 + ks * 32 + g * 8];

  __syncthreads();  // A staged

  float m[2] = {-3e38f, -3e38f}, ls[2] = {0.f, 0.f}, vv[2] = {0.f, 0.f};

#define COMPUTE_CHUNK(c)                                                       \
  {                                                                            \
    bf16x8 a0[4], a1[4];                                                       \
    _Pragma("unroll") for (int j = 0; j < 4; ++j) {                            \
      a0[j] = *(const bf16x8*)&KS[(c) * 64 + j * 16 + r16][g * 8];             \
      a1[j] = *(const bf16x8*)&KS[(c) * 64 + j * 16 + r16][32 + g * 8];        \
    }                                                                          \
    float4 bs4[4], vw4[4];                                                     \
    _Pragma("unroll") for (int j = 0; j < 4; ++j) {                            \
      bs4[j] = *(const float4*)&biasS[(c) * 64 + j * 16 + g * 4];              \
      vw4[j] = *(const float4*)&VwS[(c) * 64 + j * 16 + g * 4];                \
    }                                                                          \
    _Pragma("unroll") for (int qt = 0; qt < 2; ++qt) {                         \
      f32x4 sc[4];                                                             \
      _Pragma("unroll") for (int j = 0; j < 4; ++j) {                          \
        f32x4 z = (f32x4){bs4[j].x, bs4[j].y, bs4[j].z, bs4[j].w};             \
        z = __builtin_amdgcn_mfma_f32_16x16x32_bf16(a0[j], qf[qt][0], z, 0, 0, 0); \
        z = __builtin_amdgcn_mfma_f32_16x16x32_bf16(a0[j], qf[qt][1], z, 0, 0, 0); \
        z = __builtin_amdgcn_mfma_f32_16x16x32_bf16(a1[j], qf[qt][0], z, 0, 0, 0); \
        sc[j] = z;                                                             \
      }                                                                        \
      float cm01 = fmaxf(fmaxf(sc[0][0], sc[0][1]), fmaxf(sc[0][2], sc[0][3])); \
      float cm23 = fmaxf(fmaxf(sc[1][0], sc[1][1]), fmaxf(sc[1][2], sc[1][3])); \
      float cm45 = fmaxf(fmaxf(sc[2][0], sc[2][1]), fmaxf(sc[2][2], sc[2][3])); \
      float cm67 = fmaxf(fmaxf(sc[3][0], sc[3][1]), fmaxf(sc[3][2], sc[3][3])); \
      const float cmax = fmaxf(fmaxf(cm01, cm23), fmaxf(cm45, cm67));          \
      const float mnew = fmaxf(m[qt], cmax);                                   \
      const float fsc = __builtin_amdgcn_exp2f(m[qt] - mnew);                  \
      m[qt] = mnew;                                                            \
      float l = ls[qt] * fsc, v = vv[qt] * fsc;                                \
      _Pragma("unroll") for (int j = 0; j < 4; ++j) {                          \
        const float p0 = __builtin_amdgcn_exp2f(sc[j][0] - mnew);              \
        const float p1 = __builtin_amdgcn_exp2f(sc[j][1] - mnew);              \
        const float p2 = __builtin_amdgcn_exp2f(sc[j][2] - mnew);              \
        const float p3 = __builtin_amdgcn_exp2f(sc[j][3] - mnew);              \
        l += (p0 + p1) + (p2 + p3);                                            \
        v = fmaf(p0, vw4[j].x, v);                                             \
        v = fmaf(p1, vw4[j].y, v);                                             \
        v = fmaf(p2, vw4[j].z, v);                                             \
        v = fmaf(p3, vw4[j].w, v);                                             \
      }                                                                        \
      ls[qt] = l; vv[qt] = v;                                                  \
    }                                                                          \
  }

  COMPUTE_CHUNK(0)
  COMPUTE_CHUNK(1)
  COMPUTE_CHUNK(2)
  COMPUTE_CHUNK(3)

  // write B (disjoint LDS rows 256..511; no barrier needed before writes)
  {
    const int f2 = 2048 + t, f3 = 3072 + t;
    *(ushort8*)&KS[f2 >> 3][(f2 & 7) * 8] = kB0;
    *(ushort8*)&KS[f3 >> 3][(f3 & 7) * 8] = kB1;
  }
  if (t < 256) VwS[256 + t] = vwB;
  else if (t < 512) biasS[256 + (t - 256)] = biasB;
  __syncthreads();  // B staged

  COMPUTE_CHUNK(4)
  COMPUTE_CHUNK(5)
  COMPUTE_CHUNK(6)
  COMPUTE_CHUNK(7)
#undef COMPUTE_CHUNK

  // split-softmax merge across the 4 lane groups (xor 16, then 32)
#pragma unroll
  for (int qt = 0; qt < 2; ++qt) {
#pragma unroll
    for (int off = 16; off <= 32; off <<= 1) {
      const float mo = __shfl_xor(m[qt], off);
      const float lo_ = __shfl_xor(ls[qt], off);
      const float vo = __shfl_xor(vv[qt], off);
      const float m2 = fmaxf(m[qt], mo);
      const float fa = __builtin_amdgcn_exp2f(m[qt] - m2);
      const float fb = __builtin_amdgcn_exp2f(mo - m2);
      ls[qt] = ls[qt] * fa + lo_ * fb;
      vv[qt] = vv[qt] * fa + vo * fb;
      m[qt] = m2;
    }
  }
  if (lane < 16) {
#pragma unroll
    for (int qt = 0; qt < 2; ++qt)
      vws[headoff + w * 32 + qt * 16 + lane] = vv[qt] / ls[qt];
  }
}

__global__ __launch_bounds__(512) void final_kernel(
    const float* __restrict__ vws, const int* __restrict__ mask,
    float* __restrict__ out) {
  const int b = blockIdx.x, l = threadIdx.x;  // grid 32, block 512
  __shared__ float redm[8], reds[8];
  float v = 0.f;
#pragma unroll
  for (int h = 0; h < 8; ++h) v += vws[(size_t)(b * 8 + h) * 512 + l];
  if (mask[b * 512 + l] == 0) v = NEG;
  float mx = v;
#pragma unroll
  for (int off = 32; off >= 1; off >>= 1) mx = fmaxf(mx, __shfl_xor(mx, off));
  if ((l & 63) == 0) redm[l >> 6] = mx;
  __syncthreads();
  float M = redm[0];
#pragma unroll
  for (int i = 1; i < 8; ++i) M = fmaxf(M, redm[i]);
  const float e = __expf(v - M);
  float sm = e;
#pragma unroll
  for (int off = 32; off >= 1; off >>= 1) sm += __shfl_xor(sm, off);
  if ((l & 63) == 0) reds[l >> 6] = sm;
  __syncthreads();
  float S = 0.f;
#pragma unroll
  for (int i = 0; i < 8; ++i) S += reds[i];
  out[b * 512 + l] = e / S;
}

extern "C" void kernel_launch(void* const* d_in, const int* in_sizes, int n_in,
                              void* d_out, int out_size, void* d_ws, size_t ws_size,
                              hipStream_t stream) {
  const float* X  = (const float*)d_in[0];
  const int*  mk  = (const int*)d_in[1];
  const float* W1 = (const float*)d_in[2];
  const float* W2 = (const float*)d_in[3];
  const float* W3 = (const float*)d_in[4];
  const float* w  = (const float*)d_in[5];
  float* out = (float*)d_out;

  char* ws = (char*)d_ws;
  unsigned short* X2 = (unsigned short*)ws;                 // 16384*256  = 8 MB
  unsigned short* Wc = X2 + (size_t)16384 * 256;            //   576*256  = 288 KB
  unsigned short* Q2 = Wc + (size_t)576 * 256;              // 32*8*512*64 = 16 MB
  unsigned short* K2 = Q2 + (size_t)32 * 8 * 512 * 64;      // 16 MB
  float* Vw  = (float*)(K2 + (size_t)32 * 8 * 512 * 64);    // 512 KB
  float* vws = Vw + (size_t)32 * 8 * 512;                   // 512 KB

  convert_kernel<<<dim3(1057), dim3(256), 0, stream>>>(X, W1, W2, W3, w, X2, Wc);
  proj_kernel<<<dim3(256, 9), dim3(256), 0, stream>>>(X2, Wc, Q2, K2, Vw);
  attn_kernel<<<dim3(256), dim3(1024), 0, stream>>>(Q2, K2, Vw, mk, vws);
  final_kernel<<<dim3(32), dim3(512), 0, stream>>>(vws, mk, out);
}

// Round 12
// 61.018 us; speedup vs baseline: 2.3033x; 1.4160x over previous
//
#include <hip/hip_runtime.h>
#include <hip/hip_bf16.h>

// AttentionNTKChoiceModel — r12: r9 base; attn = one block per (b,h), 512 thr,
// 4 qtiles/wave, whole-head staged ONCE, no VGPR cap (r11's spill fixed:
// nothing staged is held in registers across compute).
// Measured budget (r10): attn 25.8us, rest ~37us.
// B=32, L=512, D=128, H=8, D0=D2=32.

typedef __attribute__((ext_vector_type(8))) short bf16x8;
typedef __attribute__((ext_vector_type(4))) float f32x4;
typedef __attribute__((ext_vector_type(8))) unsigned short ushort8;
typedef __attribute__((ext_vector_type(4))) unsigned short ushort4v;

#define NEG (-10000.0f)
#define LOG2E 1.4426950408889634f
#define QSCALE (0.17677669529663687f * LOG2E)

__device__ __forceinline__ unsigned short bf16_rn(float x, float* rep) {
  unsigned u = __float_as_uint(x);
  unsigned r = (u + 0x7FFFu + ((u >> 16) & 1u)) >> 16;
  *rep = __uint_as_float(r << 16);
  return (unsigned short)r;
}

// grid 1057 x 256: [0,1024) X-split, [1024,1056) W1/W2-split, 1056 u+pad
__global__ __launch_bounds__(256) void convert_kernel(
    const float* __restrict__ X, const float* __restrict__ W1,
    const float* __restrict__ W2, const float* __restrict__ W3,
    const float* __restrict__ w,
    unsigned short* __restrict__ X2, unsigned short* __restrict__ Wc) {
  const int bx = blockIdx.x, t = threadIdx.x;
  if (bx < 1056) {
    const float* src;
    unsigned short* dst;
    int row, c;
    if (bx < 1024) {
      const size_t flat = (size_t)bx * 2048 + t * 8;
      row = (int)(flat >> 7); c = (int)(flat & 127);
      src = &X[flat];
      dst = &X2[(size_t)row * 256 + c];
    } else {
      const int flat = (bx - 1024) * 2048 + t * 8;
      row = flat >> 7; c = flat & 127;
      src = (row < 256) ? &W1[(size_t)row * 128 + c]
                        : &W2[(size_t)(row - 256) * 128 + c];
      dst = &Wc[(size_t)row * 256 + c];
    }
    float xv[8];
    *(float4*)&xv[0] = *(const float4*)src;
    *(float4*)&xv[4] = *(const float4*)(src + 4);
    ushort8 hi, lo;
#pragma unroll
    for (int i = 0; i < 8; ++i) {
      float hf, lf;
      hi[i] = bf16_rn(xv[i], &hf);
      lo[i] = bf16_rn(xv[i] - hf, &lf);
    }
    *(ushort8*)dst = hi;
    *(ushort8*)(dst + 128) = lo;
  } else {
    __shared__ float uS[8][128];
    if (t < 128) {
#pragma unroll
      for (int h = 0; h < 8; ++h) {
        float acc = 0.f;
#pragma unroll
        for (int d = 0; d < 32; ++d)
          acc += W3[(h * 32 + d) * 128 + t] * w[h * 32 + d];
        uS[h][t] = acc * 0.3535533905932738f;  // 1/sqrt(8)
      }
    }
    __syncthreads();
    {
      const int r = t >> 5, c = (t & 31) * 4;
      float4 v = *(float4*)&uS[r][c];
      float vv[4] = {v.x, v.y, v.z, v.w};
      ushort4v hi, lo;
#pragma unroll
      for (int i = 0; i < 4; ++i) {
        float hf, lf;
        hi[i] = bf16_rn(vv[i], &hf);
        lo[i] = bf16_rn(vv[i] - hf, &lf);
      }
      *(ushort4v*)&Wc[(size_t)(512 + r) * 256 + c] = hi;
      *(ushort4v*)&Wc[(size_t)(512 + r) * 256 + 128 + c] = lo;
    }
    const ushort8 z = {};
    for (int i = t; i < 1792; i += 256)  // zero rows 520..575
      *(ushort8*)&Wc[(size_t)520 * 256 + i * 8] = z;
  }
}

// [16384,576] GEMM, exact 4-term: diag (hh+ll) + shifted (hl+lh).
// Block 256thr (4 waves), tile 64x64, K chunks of 64 over the 256-wide [hi|lo].
__global__ __launch_bounds__(256) void proj_kernel(
    const unsigned short* __restrict__ X2, const unsigned short* __restrict__ Wc,
    unsigned short* __restrict__ Q2, unsigned short* __restrict__ K2,
    float* __restrict__ Vw) {
  __shared__ unsigned short XS[64][72], WSd[64][72], WSx[64][72];
  const int t = threadIdx.x;
  const int row0 = blockIdx.x * 64, col0 = blockIdx.y * 64;
  const int w = t >> 6, lane = t & 63, g = lane >> 4, r16 = lane & 15;
  const int srow = t >> 2, su = (t & 3) * 16;

  f32x4 acc[4];
#pragma unroll
  for (int n = 0; n < 4; ++n) acc[n] = (f32x4){0.f, 0.f, 0.f, 0.f};

  for (int kc = 0; kc < 256; kc += 64) {
    const int kcx = (kc + 128) & 255;
    if (kc) __syncthreads();
    {
      const size_t xo = (size_t)(row0 + srow) * 256 + kc + su;
      const size_t wd = (size_t)(col0 + srow) * 256 + kc + su;
      const size_t wx = (size_t)(col0 + srow) * 256 + kcx + su;
      ushort8 a = *(const ushort8*)&X2[xo];
      ushort8 b = *(const ushort8*)&X2[xo + 8];
      ushort8 c = *(const ushort8*)&Wc[wd];
      ushort8 d = *(const ushort8*)&Wc[wd + 8];
      ushort8 e = *(const ushort8*)&Wc[wx];
      ushort8 f = *(const ushort8*)&Wc[wx + 8];
      *(ushort8*)&XS[srow][su] = a;
      *(ushort8*)&XS[srow][su + 8] = b;
      *(ushort8*)&WSd[srow][su] = c;
      *(ushort8*)&WSd[srow][su + 8] = d;
      *(ushort8*)&WSx[srow][su] = e;
      *(ushort8*)&WSx[srow][su + 8] = f;
    }
    __syncthreads();
#pragma unroll
    for (int ks = 0; ks < 2; ++ks) {
      bf16x8 ah = *(const bf16x8*)&XS[w * 16 + r16][ks * 32 + g * 8];
#pragma unroll
      for (int n = 0; n < 4; ++n) {
        bf16x8 bd = *(const bf16x8*)&WSd[n * 16 + r16][ks * 32 + g * 8];
        bf16x8 bx = *(const bf16x8*)&WSx[n * 16 + r16][ks * 32 + g * 8];
        acc[n] = __builtin_amdgcn_mfma_f32_16x16x32_bf16(ah, bd, acc[n], 0, 0, 0);
        acc[n] = __builtin_amdgcn_mfma_f32_16x16x32_bf16(ah, bx, acc[n], 0, 0, 0);
      }
    }
  }
  // C layout: row = w*16 + g*4 + r, col = col0 + n*16 + r16 (verified r2)
#pragma unroll
  for (int n = 0; n < 4; ++n) {
    const int col = col0 + n * 16 + r16;
#pragma unroll
    for (int r = 0; r < 4; ++r) {
      const int row = row0 + w * 16 + g * 4 + r;
      const int b = row >> 9, l = row & 511;
      const float val = acc[n][r];
      if (col < 256) {
        const float sv = val * QSCALE;
        float hf, lf;
        const unsigned short hb = bf16_rn(sv, &hf);
        const unsigned short lb = bf16_rn(sv - hf, &lf);
        const size_t o = ((size_t)(b * 8 + (col >> 5)) * 512 + l) * 64 + (col & 31);
        Q2[o] = hb; Q2[o + 32] = lb;
      } else if (col < 512) {
        const int c2 = col - 256;
        float hf, lf;
        const unsigned short hb = bf16_rn(val, &hf);
        const unsigned short lb = bf16_rn(val - hf, &lf);
        const size_t o = ((size_t)(b * 8 + (c2 >> 5)) * 512 + l) * 64 + (c2 & 31);
        K2[o] = hb; K2[o + 32] = lb;
      } else if (col < 520) {
        Vw[(size_t)(b * 8 + (col - 512)) * 512 + l] = val;
      }
    }
  }
}

// One block per (b,h): 512 thr (8 waves), wave owns 64 q rows (4 qtiles).
// Whole 512-key head staged ONCE in LDS; single barrier; lane-local softmax.
__global__ __launch_bounds__(512) void attn_kernel(
    const unsigned short* __restrict__ Q2, const unsigned short* __restrict__ K2,
    const float* __restrict__ Vw, const int* __restrict__ mask,
    float* __restrict__ vws) {
  __shared__ unsigned short KS[512][72];  // 73,728 B
  __shared__ float VwS[512], biasS[512];
  const int t = threadIdx.x;
  const int w = t >> 6, lane = t & 63, g = lane >> 4, r16 = lane & 15;
  const int head = blockIdx.x;  // b*8 + h
  const int b = head >> 3;
  const size_t headoff = (size_t)head * 512;

#pragma unroll
  for (int i = 0; i < 8; ++i) {
    const int flat = i * 512 + t, row = flat >> 3, cg = (flat & 7) * 8;
    *(ushort8*)&KS[row][cg] = *(const ushort8*)&K2[(headoff + row) * 64 + cg];
  }
  VwS[t] = Vw[headoff + t];
  biasS[t] = mask[b * 512 + t] ? 0.f : NEG * LOG2E;

  bf16x8 qf[4][2];  // [qtile][hi/lo] — wave w owns q rows w*64 .. w*64+63
#pragma unroll
  for (int qt = 0; qt < 4; ++qt)
#pragma unroll
    for (int ks = 0; ks < 2; ++ks)
      qf[qt][ks] = *(const bf16x8*)
          &Q2[(headoff + w * 64 + qt * 16 + r16) * 64 + ks * 32 + g * 8];

  __syncthreads();

  float m[4], ls[4], vv[4];
#pragma unroll
  for (int qt = 0; qt < 4; ++qt) { m[qt] = -3e38f; ls[qt] = 0.f; vv[qt] = 0.f; }

  for (int c = 0; c < 8; ++c) {
    bf16x8 a0[4], a1[4];
#pragma unroll
    for (int j = 0; j < 4; ++j) {
      a0[j] = *(const bf16x8*)&KS[c * 64 + j * 16 + r16][g * 8];
      a1[j] = *(const bf16x8*)&KS[c * 64 + j * 16 + r16][32 + g * 8];
    }
    float4 bs4[4], vw4[4];
#pragma unroll
    for (int j = 0; j < 4; ++j) {
      bs4[j] = *(const float4*)&biasS[c * 64 + j * 16 + g * 4];
      vw4[j] = *(const float4*)&VwS[c * 64 + j * 16 + g * 4];
    }
#pragma unroll
    for (int qt = 0; qt < 4; ++qt) {
      f32x4 sc[4];
#pragma unroll
      for (int j = 0; j < 4; ++j) {
        f32x4 z = (f32x4){bs4[j].x, bs4[j].y, bs4[j].z, bs4[j].w};  // bias in C
        z = __builtin_amdgcn_mfma_f32_16x16x32_bf16(a0[j], qf[qt][0], z, 0, 0, 0);
        z = __builtin_amdgcn_mfma_f32_16x16x32_bf16(a0[j], qf[qt][1], z, 0, 0, 0);
        z = __builtin_amdgcn_mfma_f32_16x16x32_bf16(a1[j], qf[qt][0], z, 0, 0, 0);
        sc[j] = z;
      }
      float cm01 = fmaxf(fmaxf(sc[0][0], sc[0][1]), fmaxf(sc[0][2], sc[0][3]));
      float cm23 = fmaxf(fmaxf(sc[1][0], sc[1][1]), fmaxf(sc[1][2], sc[1][3]));
      float cm45 = fmaxf(fmaxf(sc[2][0], sc[2][1]), fmaxf(sc[2][2], sc[2][3]));
      float cm67 = fmaxf(fmaxf(sc[3][0], sc[3][1]), fmaxf(sc[3][2], sc[3][3]));
      const float cmax = fmaxf(fmaxf(cm01, cm23), fmaxf(cm45, cm67));
      const float mnew = fmaxf(m[qt], cmax);
      const float f = __builtin_amdgcn_exp2f(m[qt] - mnew);
      m[qt] = mnew;
      float l = ls[qt] * f, v = vv[qt] * f;
#pragma unroll
      for (int j = 0; j < 4; ++j) {
        const float p0 = __builtin_amdgcn_exp2f(sc[j][0] - mnew);
        const float p1 = __builtin_amdgcn_exp2f(sc[j][1] - mnew);
        const float p2 = __builtin_amdgcn_exp2f(sc[j][2] - mnew);
        const float p3 = __builtin_amdgcn_exp2f(sc[j][3] - mnew);
        l += (p0 + p1) + (p2 + p3);
        v = fmaf(p0, vw4[j].x, v);
        v = fmaf(p1, vw4[j].y, v);
        v = fmaf(p2, vw4[j].z, v);
        v = fmaf(p3, vw4[j].w, v);
      }
      ls[qt] = l; vv[qt] = v;
    }
  }
  // split-softmax merge across the 4 lane groups (xor 16, then 32)
#pragma unroll
  for (int qt = 0; qt < 4; ++qt) {
#pragma unroll
    for (int off = 16; off <= 32; off <<= 1) {
      const float mo = __shfl_xor(m[qt], off);
      const float lo_ = __shfl_xor(ls[qt], off);
      const float vo = __shfl_xor(vv[qt], off);
      const float m2 = fmaxf(m[qt], mo);
      const float fa = __builtin_amdgcn_exp2f(m[qt] - m2);
      const float fb = __builtin_amdgcn_exp2f(mo - m2);
      ls[qt] = ls[qt] * fa + lo_ * fb;
      vv[qt] = vv[qt] * fa + vo * fb;
      m[qt] = m2;
    }
  }
  if (lane < 16) {
#pragma unroll
    for (int qt = 0; qt < 4; ++qt)
      vws[headoff + w * 64 + qt * 16 + lane] = vv[qt] / ls[qt];
  }
}

__global__ __launch_bounds__(512) void final_kernel(
    const float* __restrict__ vws, const int* __restrict__ mask,
    float* __restrict__ out) {
  const int b = blockIdx.x, l = threadIdx.x;  // grid 32, block 512
  __shared__ float redm[8], reds[8];
  float v = 0.f;
#pragma unroll
  for (int h = 0; h < 8; ++h) v += vws[(size_t)(b * 8 + h) * 512 + l];
  if (mask[b * 512 + l] == 0) v = NEG;
  float mx = v;
#pragma unroll
  for (int off = 32; off >= 1; off >>= 1) mx = fmaxf(mx, __shfl_xor(mx, off));
  if ((l & 63) == 0) redm[l >> 6] = mx;
  __syncthreads();
  float M = redm[0];
#pragma unroll
  for (int i = 1; i < 8; ++i) M = fmaxf(M, redm[i]);
  const float e = __expf(v - M);
  float sm = e;
#pragma unroll
  for (int off = 32; off >= 1; off >>= 1) sm += __shfl_xor(sm, off);
  if ((l & 63) == 0) reds[l >> 6] = sm;
  __syncthreads();
  float S = 0.f;
#pragma unroll
  for (int i = 0; i < 8; ++i) S += reds[i];
  out[b * 512 + l] = e / S;
}

extern "C" void kernel_launch(void* const* d_in, const int* in_sizes, int n_in,
                              void* d_out, int out_size, void* d_ws, size_t ws_size,
                              hipStream_t stream) {
  const float* X  = (const float*)d_in[0];
  const int*  mk  = (const int*)d_in[1];
  const float* W1 = (const float*)d_in[2];
  const float* W2 = (const float*)d_in[3];
  const float* W3 = (const float*)d_in[4];
  const float* w  = (const float*)d_in[5];
  float* out = (float*)d_out;

  char* ws = (char*)d_ws;
  unsigned short* X2 = (unsigned short*)ws;                 // 16384*256  = 8 MB
  unsigned short* Wc = X2 + (size_t)16384 * 256;            //   576*256  = 288 KB
  unsigned short* Q2 = Wc + (size_t)576 * 256;              // 32*8*512*64 = 16 MB
  unsigned short* K2 = Q2 + (size_t)32 * 8 * 512 * 64;      // 16 MB
  float* Vw  = (float*)(K2 + (size_t)32 * 8 * 512 * 64);    // 512 KB
  float* vws = Vw + (size_t)32 * 8 * 512;                   // 512 KB

  convert_kernel<<<dim3(1057), dim3(256), 0, stream>>>(X, W1, W2, W3, w, X2, Wc);
  proj_kernel<<<dim3(256, 9), dim3(256), 0, stream>>>(X2, Wc, Q2, K2, Vw);
  attn_kernel<<<dim3(256), dim3(512), 0, stream>>>(Q2, K2, Vw, mk, vws);
  final_kernel<<<dim3(32), dim3(512), 0, stream>>>(vws, mk, out);
}